// Round 2
// baseline (38.997 us; speedup 1.0000x reference)
//
#include <hip/hip_runtime.h>
#include <hip/hip_cooperative_groups.h>

namespace cg = cooperative_groups;

// HEX loss collapses analytically: pot[k,i,j,b] = exp(s_i*e_k)*exp(s_j*e_{k+1})
// has no i-j coupling; numVar=[1,2,...,2,1] exactly cancels the per-edge
// double-counting of node factors, so pMargin[v,b] = sigmoid(fs[b,v]) and
// loss = mean_b softplus(-fs[b, labels[b]]).
//
// Single cooperative dispatch: per-block partial reduce -> grid.sync() ->
// block 0 final reduce. (Atomic-counter schemes are replay-unsafe: d_ws is
// poisoned once after the correctness call and never re-poisoned.)

__global__ void hex_fused_kernel(const float* __restrict__ fs,
                                 const int* __restrict__ labels,
                                 double* __restrict__ partial,
                                 float* __restrict__ out,
                                 int Bn, int Vn) {
    __shared__ float sdata[256];
    __shared__ double ddata[256];

    const int tid = threadIdx.x;
    const int b = blockIdx.x * blockDim.x + tid;

    float l = 0.0f;
    if (b < Bn) {
        const int lab = labels[b];
        const float x = fs[(size_t)b * (size_t)Vn + (size_t)lab];
        // softplus(-x) = -log(sigmoid(x)), numerically stable split (f32 is
        // plenty: abs error on the mean ~1e-6 vs 1.6e-2 threshold)
        l = (x > 0.0f) ? log1pf(expf(-x)) : (-x + log1pf(expf(x)));
    }
    sdata[tid] = l;
    __syncthreads();
    for (int off = blockDim.x >> 1; off > 0; off >>= 1) {
        if (tid < off) sdata[tid] += sdata[tid + off];
        __syncthreads();
    }
    if (tid == 0) partial[blockIdx.x] = (double)sdata[0];

    cg::this_grid().sync();

    if (blockIdx.x == 0) {
        double s = 0.0;
        for (int i = tid; i < gridDim.x; i += blockDim.x) s += partial[i];
        ddata[tid] = s;
        __syncthreads();
        for (int off = blockDim.x >> 1; off > 0; off >>= 1) {
            if (tid < off) ddata[tid] += ddata[tid + off];
            __syncthreads();
        }
        if (tid == 0) out[0] = (float)(ddata[0] / (double)Bn);
    }
}

extern "C" void kernel_launch(void* const* d_in, const int* in_sizes, int n_in,
                              void* d_out, int out_size, void* d_ws, size_t ws_size,
                              hipStream_t stream) {
    const float* fs = (const float*)d_in[0];
    const int* labels = (const int*)d_in[1];
    float* out = (float*)d_out;

    int Bn = in_sizes[1];            // 32768 labels
    int Vn = in_sizes[0] / Bn;       // 256
    double* partial = (double*)d_ws; // 128 * 8 B scratch

    int threads = 256;
    int blocks = (Bn + threads - 1) / threads;  // 128 — co-resident on 256 CUs

    void* args[] = {(void*)&fs, (void*)&labels, (void*)&partial,
                    (void*)&out, (void*)&Bn, (void*)&Vn};
    hipLaunchCooperativeKernel((const void*)hex_fused_kernel,
                               dim3(blocks), dim3(threads), args, 0, stream);
}